// Round 11
// baseline (429.323 us; speedup 1.0000x reference)
//
#include <hip/hip_runtime.h>
#include <hip/hip_cooperative_groups.h>

namespace cg = cooperative_groups;

// ---------------------------------------------------------------------------
// HiPPO-LegT via scalar-kernel convolution, 2 launches:
//   pred[b][t] = fac_t * sum_{s<=t} k[t-s] x[b][s] + D x[b][t],  k[tau]=C A^tau B
// Launch 1: cooperative genk2 (256 blk x 512 thr, 13 phases / 12 grid.syncs).
//   NO serial chains: W and V are built by PARALLEL DOUBLING (matmul steps),
//   so every phase is register-light (no areg[] arrays -> no spill).
//     W[0]=C; W[n..2n) = W[0..n) * A^n         (n = 1,2,4,8,16,32)
//     V[0]=B; V[n..2n) = V[0..n) * P(64n)^T    (n = 1,2,4,8,16,32)
//   Squaring ladder: P2,P4,P8,P16,P32 | P64T=(P32^2)^T | P128T..P2048T = T^2.
//   kfrag (K dots + Toeplitz bf16 A-fragments, validated r8-r10) is phase 12.
// Launch 2: convm — validated MFMA Toeplitz GEMM (r4/r10).
// Fallback if coop launch fails: genk2 replayed per-phase (stream-ordered).
// ---------------------------------------------------------------------------

#define LENGTH 4096

// ws float offsets (power slots reused after last read)
#define WS_S0    0         // P2   -> P256T
#define WS_S1    65536     // P4   -> P512T
#define WS_S2    131072    // P8   -> P1024T
#define WS_S3    196608    // P16  -> P2048T
#define WS_P32   262144
#define WS_P64T  327680
#define WS_P128T 393216
#define WS_W     458752    // 64 x 256
#define WS_V     475136    // 64 x 256
#define WS_XH    491520    // 1M shorts = 524288 floats
#define WS_XL    1015808
#define WS_AH    1540096   // 128K shorts = 65536 floats
#define WS_AL    1605632

typedef __attribute__((ext_vector_type(8))) short bf16x8;
typedef __attribute__((ext_vector_type(4))) float f32x4;
#define MFMA(a, b, c) __builtin_amdgcn_mfma_f32_16x16x32_bf16(a, b, c, 0, 0, 0)

__device__ inline unsigned short f2bf(float f) {
    unsigned int u = __float_as_uint(f);
    return (unsigned short)((u + 0x7FFFu + ((u >> 16) & 1u)) >> 16);
}
__device__ inline void split2(float f, short& h, short& l) {
    unsigned short hu = f2bf(f);
    float fh = __uint_as_float((unsigned int)hu << 16);
    h = (short)hu;
    l = (short)f2bf(f - fh);
}

// ---- 4-row squaring slice: Z rows rowb..rowb+3 of S*S; 512 thr, k-split 2 ----
__device__ __forceinline__ void sq4(const float* __restrict__ S,
                                    float* __restrict__ Z,
                                    int rowb, int t, bool trans, float* shm) {
    const int j = t & 255, p = t >> 8;
    float* Xl  = shm;          // 1024
    float* red = shm + 1024;   // 2048
    for (int u = t; u < 1024; u += 512) Xl[u] = S[rowb * 256 + u];
    __syncthreads();
    float a0 = 0.f, a1 = 0.f, a2 = 0.f, a3 = 0.f;
    const float* yc = S + (128 * p) * 256 + j;
    const float* xl = Xl + 128 * p;
#pragma unroll 8
    for (int l = 0; l < 128; ++l) {
        const float yv = yc[l * 256];
        a0 = fmaf(xl[l],       yv, a0);
        a1 = fmaf(xl[256 + l], yv, a1);
        a2 = fmaf(xl[512 + l], yv, a2);
        a3 = fmaf(xl[768 + l], yv, a3);
    }
    __syncthreads();
    red[p * 1024 +       j] = a0;
    red[p * 1024 + 256 + j] = a1;
    red[p * 1024 + 512 + j] = a2;
    red[p * 1024 + 768 + j] = a3;
    __syncthreads();
    if (!p) {
        const float z0 = red[j]       + red[1024 + j];
        const float z1 = red[256 + j] + red[1280 + j];
        const float z2 = red[512 + j] + red[1536 + j];
        const float z3 = red[768 + j] + red[1792 + j];
        if (trans) {
            float4 v = {z0, z1, z2, z3};
            *reinterpret_cast<float4*>(Z + j * 256 + rowb) = v;
        } else {
            Z[(rowb + 0) * 256 + j] = z0;
            Z[(rowb + 1) * 256 + j] = z1;
            Z[(rowb + 2) * 256 + j] = z2;
            Z[(rowb + 3) * 256 + j] = z3;
        }
    }
    __syncthreads();
}

// ---- out[j] = sum_i v[i] * M[i*256+j]; 512 thr, k-split 2 (coalesced M) ----
__device__ __forceinline__ void vecmat(const float* __restrict__ v,
                                       const float* __restrict__ M,
                                       float* __restrict__ out,
                                       int t, float* shm) {
    const int j = t & 255, p = t >> 8;
    float* red = shm;   // 256
    float s0 = 0.f, s1 = 0.f;
#pragma unroll 8
    for (int ii = 0; ii < 128; ii += 2) {
        s0 = fmaf(v[128 * p + ii],     M[(128 * p + ii) * 256 + j],     s0);
        s1 = fmaf(v[128 * p + ii + 1], M[(128 * p + ii + 1) * 256 + j], s1);
    }
    const float s = s0 + s1;
    __syncthreads();
    if (p) red[j] = s;
    __syncthreads();
    if (!p) out[j] = s + red[j];
    __syncthreads();
}

// ===========================================================================
// genk2: generation by parallel doubling. ph < 0: cooperative (grid.sync);
// ph = 0..12: run only that phase (fallback, stream-ordered launches).
// ===========================================================================
__global__ __launch_bounds__(512) void genk2(const float* __restrict__ x,
                                             const float* __restrict__ A,
                                             const float* __restrict__ B,
                                             const float* __restrict__ C,
                                             float* __restrict__ ws,
                                             int ph) {
    const bool coop = (ph < 0);
    cg::grid_group grid = cg::this_grid();
    const int bid = blockIdx.x;
    const int t = threadIdx.x;

    __shared__ __align__(16) float shm[17408];   // kfrag needs 17376 floats

    float* P2    = ws + WS_S0;
    float* P4    = ws + WS_S1;
    float* P8    = ws + WS_S2;
    float* P16   = ws + WS_S3;
    float* P32   = ws + WS_P32;
    float* P64T  = ws + WS_P64T;
    float* P128T = ws + WS_P128T;
    float* P256T  = ws + WS_S0;   // reuse: P2 dead after ph1
    float* P512T  = ws + WS_S1;   // P4 dead after ph2
    float* P1024T = ws + WS_S2;   // P8 dead after ph3
    float* P2048T = ws + WS_S3;   // P16 dead after ph4
    float* Wm    = ws + WS_W;
    float* Vm    = ws + WS_V;
    short* XH    = (short*)(ws + WS_XH);
    short* XL    = (short*)(ws + WS_XL);
    short* AH    = (short*)(ws + WS_AH);
    short* AL    = (short*)(ws + WS_AL);

    // ---- ph0: xsplit (all blocks) + P2 = A*A + W[0]=C, W[1]=C*A ----
    if (coop || ph == 0) {
        {
            const int wv = t >> 6, lane = t & 63;
            const int pj = bid * 8 + wv;                 // 0..2047
            const int c = pj >> 4, blk = pj & 15;
            const int b = blk * 16 + (lane & 15);
            const int s0 = c * 32 + 8 * (lane >> 4);
            const float4 v0 = reinterpret_cast<const float4*>(&x[b * LENGTH + s0])[0];
            const float4 v1 = reinterpret_cast<const float4*>(&x[b * LENGTH + s0])[1];
            const float f[8] = {v0.x, v0.y, v0.z, v0.w, v1.x, v1.y, v1.z, v1.w};
            bf16x8 hv, lv;
#pragma unroll
            for (int e = 0; e < 8; ++e) {
                short h_, l_;
                split2(f[e], h_, l_);
                hv[e] = h_; lv[e] = l_;
            }
            const int off = (pj * 64 + lane) * 8;
            *reinterpret_cast<bf16x8*>(XH + off) = hv;
            *reinterpret_cast<bf16x8*>(XL + off) = lv;
        }
        if (bid < 64) sq4(A, P2, 4 * bid, t, false, shm);
        else if (bid == 64) { if (t < 256) Wm[t] = C[t]; }
        else if (bid == 65) vecmat(C, A, Wm + 256, t, shm);
    }
    if (coop) grid.sync();
    // ---- ph1..ph4: squarings + W doubling ----
    if (coop || ph == 1) {
        if (bid < 64) sq4(P2, P4, 4 * bid, t, false, shm);
        else if (bid < 66) vecmat(Wm + (bid - 64) * 256, P2, Wm + (2 + bid - 64) * 256, t, shm);
    }
    if (coop) grid.sync();
    if (coop || ph == 2) {
        if (bid < 64) sq4(P4, P8, 4 * bid, t, false, shm);
        else if (bid < 68) vecmat(Wm + (bid - 64) * 256, P4, Wm + (4 + bid - 64) * 256, t, shm);
    }
    if (coop) grid.sync();
    if (coop || ph == 3) {
        if (bid < 64) sq4(P8, P16, 4 * bid, t, false, shm);
        else if (bid < 72) vecmat(Wm + (bid - 64) * 256, P8, Wm + (8 + bid - 64) * 256, t, shm);
    }
    if (coop) grid.sync();
    if (coop || ph == 4) {
        if (bid < 64) sq4(P16, P32, 4 * bid, t, false, shm);
        else if (bid < 80) vecmat(Wm + (bid - 64) * 256, P16, Wm + (16 + bid - 64) * 256, t, shm);
    }
    if (coop) grid.sync();
    // ---- ph5: P64T = (P32^2)^T + final W doubling ----
    if (coop || ph == 5) {
        if (bid < 64) sq4(P32, P64T, 4 * bid, t, true, shm);
        else if (bid < 96) vecmat(Wm + (bid - 64) * 256, P32, Wm + (32 + bid - 64) * 256, t, shm);
    }
    if (coop) grid.sync();
    // ---- ph6: P128T = P64T^2 + V[0]=B, V[1] = B * P64T ----
    if (coop || ph == 6) {
        if (bid < 64) sq4(P64T, P128T, 4 * bid, t, false, shm);
        else if (bid == 64) { if (t < 256) Vm[t] = B[t]; }
        else if (bid == 65) vecmat(B, P64T, Vm + 256, t, shm);
    }
    if (coop) grid.sync();
    // ---- ph7..ph10: T-squarings + V doubling ----
    if (coop || ph == 7) {
        if (bid < 64) sq4(P128T, P256T, 4 * bid, t, false, shm);
        else if (bid < 66) vecmat(Vm + (bid - 64) * 256, P128T, Vm + (2 + bid - 64) * 256, t, shm);
    }
    if (coop) grid.sync();
    if (coop || ph == 8) {
        if (bid < 64) sq4(P256T, P512T, 4 * bid, t, false, shm);
        else if (bid < 68) vecmat(Vm + (bid - 64) * 256, P256T, Vm + (4 + bid - 64) * 256, t, shm);
    }
    if (coop) grid.sync();
    if (coop || ph == 9) {
        if (bid < 64) sq4(P512T, P1024T, 4 * bid, t, false, shm);
        else if (bid < 72) vecmat(Vm + (bid - 64) * 256, P512T, Vm + (8 + bid - 64) * 256, t, shm);
    }
    if (coop) grid.sync();
    if (coop || ph == 10) {
        if (bid < 64) sq4(P1024T, P2048T, 4 * bid, t, false, shm);
        else if (bid < 80) vecmat(Vm + (bid - 64) * 256, P1024T, Vm + (16 + bid - 64) * 256, t, shm);
    }
    if (coop) grid.sync();
    // ---- ph11: V[32..64) = V[0..32) * P2048T ----
    if (coop || ph == 11) {
        if (bid < 32) vecmat(Vm + bid * 256, P2048T, Vm + (32 + bid) * 256, t, shm);
    }
    if (coop) grid.sync();
    // ---- ph12: kfrag (blocks 0..31): K dots + Toeplitz A-fragments ----
    if (coop || ph == 12) {
        if (bid < 32) {
            float* Wl = shm;             // 64 x 257 = 16448
            float* Vl = shm + 16448;     // 768
            float* kl = shm + 17216;     // 160
            for (int u = t; u < 16384; u += 512)
                Wl[(u >> 8) * 257 + (u & 255)] = Wm[u];
            for (int u = t; u < 768; u += 512) {
                const int q = 2 * bid - 1 + (u >> 8);
                Vl[u] = (q >= 0) ? Vm[q * 256 + (u & 255)] : 0.f;
            }
            __syncthreads();
            if (t < 159) {
                const int tau = 128 * bid - 31 + t;
                float s = 0.f;
                if (tau >= 0) {
                    const int r = tau & 63;
                    const int qq = (tau >> 6) - (2 * bid - 1);
                    const float* wr = &Wl[r * 257];
                    const float* vr = &Vl[qq * 256];
                    float s0 = 0.f, s1 = 0.f, s2 = 0.f, s3 = 0.f;
#pragma unroll 8
                    for (int i2 = 0; i2 < 256; i2 += 4) {
                        s0 = fmaf(wr[i2 + 0], vr[i2 + 0], s0);
                        s1 = fmaf(wr[i2 + 1], vr[i2 + 1], s1);
                        s2 = fmaf(wr[i2 + 2], vr[i2 + 2], s2);
                        s3 = fmaf(wr[i2 + 3], vr[i2 + 3], s3);
                    }
                    s = (s0 + s1) + (s2 + s3);
                }
                kl[t] = s;
            }
            __syncthreads();
            const int wv = t >> 6, lane = t & 63;
            const int m = 8 * bid + wv;
            bf16x8 hv, lv;
#pragma unroll
            for (int el = 0; el < 8; ++el) {
                const int rel = 16 * wv + (lane & 15) - 8 * (lane >> 4) - el + 31;
                short h_, l_;
                split2(kl[rel], h_, l_);          // rel always in [0,158]
                hv[el] = h_; lv[el] = l_;
            }
            const int off = (m * 64 + lane) * 8;
            *reinterpret_cast<bf16x8*>(AH + off) = hv;
            *reinterpret_cast<bf16x8*>(AL + off) = lv;
        }
    }
}

// ===========================================================================
// convm — validated (r4/r10): 256 blocks = 32 pairs x 8 btiles(32b); 8 waves
// k-split the pair's 130 chunks; double-buffered fragments; LDS reduce;
// coalesced exclusive float4 stores with D*x and t=0 fix folded in.
// ===========================================================================
struct Frag {
    bf16x8 bh0, bh1, bl0, bl1;
    bf16x8 ah0, ah1, ah2, ah3, al0, al1, al2, al3;
    int d0, tile;
};

#define LOADF(F, IDX_) do {                                                    \
        const int i_ = (IDX_);                                                 \
        const int tl_ = (i_ < nA) ? 0 : 1;                                     \
        const int cc_ = i_ - (tl_ ? nA : 0);                                   \
        const int xo_ = ((cc_ * 16 + bt2) * 64 + lane) * 8;                    \
        F.bh0 = *reinterpret_cast<const bf16x8*>(XH + xo_);                    \
        F.bh1 = *reinterpret_cast<const bf16x8*>(XH + xo_ + 512);              \
        F.bl0 = *reinterpret_cast<const bf16x8*>(XL + xo_);                    \
        F.bl1 = *reinterpret_cast<const bf16x8*>(XL + xo_ + 512);              \
        const int d_ = (tl_ ? tB64 : tA64) - cc_ * 32;                         \
        F.d0 = d_; F.tile = tl_;                                               \
        const int m0_ = (d_ > 0 ? d_ : 0) >> 4;                                \
        const int m1_ = (d_ + 16 > 0 ? d_ + 16 : 0) >> 4;                      \
        const int m2_ = (d_ + 32 > 0 ? d_ + 32 : 0) >> 4;                      \
        const int m3_ = (d_ + 48 > 0 ? d_ + 48 : 0) >> 4;                      \
        F.ah0 = *reinterpret_cast<const bf16x8*>(AH + (m0_ * 64 + lane) * 8);  \
        F.al0 = *reinterpret_cast<const bf16x8*>(AL + (m0_ * 64 + lane) * 8);  \
        F.ah1 = *reinterpret_cast<const bf16x8*>(AH + (m1_ * 64 + lane) * 8);  \
        F.al1 = *reinterpret_cast<const bf16x8*>(AL + (m1_ * 64 + lane) * 8);  \
        F.ah2 = *reinterpret_cast<const bf16x8*>(AH + (m2_ * 64 + lane) * 8);  \
        F.al2 = *reinterpret_cast<const bf16x8*>(AL + (m2_ * 64 + lane) * 8);  \
        F.ah3 = *reinterpret_cast<const bf16x8*>(AH + (m3_ * 64 + lane) * 8);  \
        F.al3 = *reinterpret_cast<const bf16x8*>(AL + (m3_ * 64 + lane) * 8);  \
    } while (0)

#define ONER(F, T, R, AHF, ALF)                                                \
        if (F.d0 + 16 * R >= 0) {                                              \
            acc[T][R][0] = MFMA(F.AHF, F.bh0, acc[T][R][0]);                   \
            acc[T][R][1] = MFMA(F.AHF, F.bh1, acc[T][R][1]);                   \
            acc[T][R][0] = MFMA(F.AHF, F.bl0, acc[T][R][0]);                   \
            acc[T][R][1] = MFMA(F.AHF, F.bl1, acc[T][R][1]);                   \
            acc[T][R][0] = MFMA(F.ALF, F.bh0, acc[T][R][0]);                   \
            acc[T][R][1] = MFMA(F.ALF, F.bh1, acc[T][R][1]);                   \
        }

#define APPLY(F) do {                                                          \
        if (F.tile == 0) {                                                     \
            ONER(F, 0, 0, ah0, al0) ONER(F, 0, 1, ah1, al1)                    \
            ONER(F, 0, 2, ah2, al2) ONER(F, 0, 3, ah3, al3)                    \
        } else {                                                               \
            ONER(F, 1, 0, ah0, al0) ONER(F, 1, 1, ah1, al1)                    \
            ONER(F, 1, 2, ah2, al2) ONER(F, 1, 3, ah3, al3)                    \
        }                                                                      \
    } while (0)

__global__ __launch_bounds__(512) void convm(const short* __restrict__ XH,
                                             const short* __restrict__ XL,
                                             const short* __restrict__ AH,
                                             const short* __restrict__ AL,
                                             const float* __restrict__ x,
                                             const float* __restrict__ Dp,
                                             float* __restrict__ out) {
    const int pr = blockIdx.x & 31;
    const int bt = blockIdx.x >> 5;
    const int tid = threadIdx.x;
    const int w = tid >> 6, lane = tid & 63;
    const int tA64 = pr * 64, tB64 = (63 - pr) * 64;
    const int nA = 2 * pr + 2;
    const int bt2 = bt * 2;

    __shared__ float lds[16 * 64 * 34];

    f32x4 acc[2][4][2];
#pragma unroll
    for (int t_ = 0; t_ < 2; ++t_)
#pragma unroll
        for (int r_ = 0; r_ < 4; ++r_)
#pragma unroll
            for (int c_ = 0; c_ < 2; ++c_) acc[t_][r_][c_] = f32x4{0.f, 0.f, 0.f, 0.f};

    Frag f0, f1;
    LOADF(f0, w);
    int idx = w;
    while (true) {
        const int n1 = idx + 8;
        const bool h1 = n1 < 130;
        if (h1) LOADF(f1, n1);
        APPLY(f0);
        if (!h1) break;
        const int n2 = n1 + 8;
        const bool h2 = n2 < 130;
        if (h2) LOADF(f0, n2);
        APPLY(f1);
        if (!h2) break;
        idx = n2;
    }

    const int lq = lane >> 4, lr = lane & 15;
#pragma unroll
    for (int t_ = 0; t_ < 2; ++t_)
#pragma unroll
        for (int r_ = 0; r_ < 4; ++r_)
#pragma unroll
            for (int c_ = 0; c_ < 2; ++c_)
#pragma unroll
                for (int e_ = 0; e_ < 4; ++e_)
                    lds[((w * 2 + t_) * 64 + (r_ * 16 + lq * 4 + e_)) * 34 +
                        (c_ * 16 + lr)] = acc[t_][r_][c_][e_];
    __syncthreads();

    const float D = Dp[0];
    const int b = tid >> 4;
    const int t4 = (tid & 15) * 4;
#pragma unroll
    for (int t_ = 0; t_ < 2; ++t_) {
        const int tbase = t_ ? tB64 : tA64;
        float s0 = 0.f, s1 = 0.f, s2 = 0.f, s3 = 0.f;
#pragma unroll
        for (int w_ = 0; w_ < 8; ++w_) {
            const float* lp = &lds[((w_ * 2 + t_) * 64 + t4) * 34 + b];
            s0 += lp[0]; s1 += lp[34]; s2 += lp[68]; s3 += lp[102];
        }
        const int g = (bt * 32 + b) * LENGTH + tbase + t4;
        const float4 xv = *reinterpret_cast<const float4*>(x + g);
        float4 o;
        o.x = 2.f * s0 + D * xv.x;
        o.y = 2.f * s1 + D * xv.y;
        o.z = 2.f * s2 + D * xv.z;
        o.w = 2.f * s3 + D * xv.w;
        if (tbase == 0 && t4 == 0) o.x -= s0;     // t==0: fac is 1, not 2
        *reinterpret_cast<float4*>(out + g) = o;
    }
}

extern "C" void kernel_launch(void* const* d_in, const int* in_sizes, int n_in,
                              void* d_out, int out_size, void* d_ws, size_t ws_size,
                              hipStream_t stream) {
    const float* x  = (const float*)d_in[0];
    const float* A  = (const float*)d_in[1];
    const float* B  = (const float*)d_in[2];
    const float* C  = (const float*)d_in[3];
    const float* Dp = (const float*)d_in[4];
    float* out = (float*)d_out;
    float* ws  = (float*)d_ws;

    short* XHs = (short*)(ws + WS_XH);
    short* XLs = (short*)(ws + WS_XL);
    short* AHs = (short*)(ws + WS_AH);
    short* ALs = (short*)(ws + WS_AL);

    int ph = -1;
    void* args[] = {(void*)&x, (void*)&A, (void*)&B, (void*)&C, (void*)&ws, (void*)&ph};
    hipError_t e = hipLaunchCooperativeKernel((const void*)genk2, dim3(256), dim3(512),
                                              args, 0, stream);
    if (e != hipSuccess) {
        // fallback: same kernel, one phase per launch (stream provides ordering)
        for (int i = 0; i <= 12; ++i)
            genk2<<<256, 512, 0, stream>>>(x, A, B, C, ws, i);
    }
    convm<<<256, 512, 0, stream>>>(XHs, XLs, AHs, ALs, x, Dp, out);
}

// Round 12
// 327.655 us; speedup vs baseline: 1.3103x; 1.3103x over previous
//
#include <hip/hip_runtime.h>

// ---------------------------------------------------------------------------
// HiPPO-LegT via scalar-kernel convolution (10-launch pipeline, no coop):
//   pred[b][t] = fac_t * sum_{s<=t} k[t-s] x[b][s] + D x[b][t],  k[tau]=C A^tau B
// k factorized: k[64q+r] = (C A^r) . (A^{64q} B) = W[r] . V[q]
//   W: 4 chains x 16 steps stepping A (starts C, C P16, C P32, C P16 P32)
//   V: 2 chains x 32 steps stepping A^128 (starts B, A^64 B via P64T)
// chains kernel is SPILL-FREE: 256 thr/block, column split 176 in VGPRs
// (cap = 65536/256 = 256, measured pattern r7-r9) + 80 rows in LDS (80 KB
// also forces 1 block/CU). Measured: spilled chain step ~1.2us, this ~0.3us.
// kfrag: fused K dots + Toeplitz bf16 A-fragments (validated r8-r10).
// convm: validated MFMA Toeplitz GEMM (r4/r10).
// ---------------------------------------------------------------------------

#define LENGTH 4096

// ws layout (float offsets)
#define WS_P2    0
#define WS_P4    65536
#define WS_P8    131072
#define WS_P16   196608
#define WS_P32   262144
#define WS_P64T  327680
#define WS_P128T 393216
#define WS_W     458752   // 64 x 256
#define WS_V     475136   // 64 x 256
#define WS_XH    491520   // 1M shorts = 524288 floats
#define WS_XL    1015808
#define WS_AH    1540096  // 128K shorts = 65536 floats
#define WS_AL    1605632

typedef __attribute__((ext_vector_type(8))) short bf16x8;
typedef __attribute__((ext_vector_type(4))) float f32x4;
#define MFMA(a, b, c) __builtin_amdgcn_mfma_f32_16x16x32_bf16(a, b, c, 0, 0, 0)

__device__ inline unsigned short f2bf(float f) {
    unsigned int u = __float_as_uint(f);
    return (unsigned short)((u + 0x7FFFu + ((u >> 16) & 1u)) >> 16);
}
__device__ inline void split2(float f, short& h, short& l) {
    unsigned short hu = f2bf(f);
    float fh = __uint_as_float((unsigned int)hu << 16);
    h = (short)hu;
    l = (short)f2bf(f - fh);
}

// ---- 256x256 row-matmul body: Z(row) = X(row) * Y; 1024 thr, k-split 4 ----
__device__ __forceinline__ void mm_body(const float* __restrict__ X,
                                        const float* __restrict__ Y,
                                        float* __restrict__ Z,
                                        int row, int t, bool trans, float* red) {
    const int j = t & 255, p = t >> 8;
    const float* xr = X + row * 256 + 64 * p;
    const float* yc = Y + (64 * p) * 256 + j;
    float a0 = 0.f, a1 = 0.f, a2 = 0.f, a3 = 0.f;
#pragma unroll
    for (int l = 0; l < 64; l += 4) {
        a0 = fmaf(xr[l + 0], yc[(l + 0) * 256], a0);
        a1 = fmaf(xr[l + 1], yc[(l + 1) * 256], a1);
        a2 = fmaf(xr[l + 2], yc[(l + 2) * 256], a2);
        a3 = fmaf(xr[l + 3], yc[(l + 3) * 256], a3);
    }
    float s = (a0 + a1) + (a2 + a3);
    if (p) red[(p - 1) * 256 + j] = s;
    __syncthreads();
    if (!p) {
        float z = s + red[j] + red[256 + j] + red[512 + j];
        if (trans) Z[j * 256 + row] = z;
        else       Z[row * 256 + j] = z;
    }
}

// ---- L0: blocks 0..127: xsplit (16 wave-jobs); blocks 128..383: P2 = A*A ----
__global__ __launch_bounds__(1024) void fused0(const float* __restrict__ A,
                                               const float* __restrict__ x,
                                               float* __restrict__ P2,
                                               short* __restrict__ XH,
                                               short* __restrict__ XL) {
    __shared__ float red[3 * 256];
    const int t = threadIdx.x;
    if (blockIdx.x >= 128) {
        mm_body(A, A, P2, blockIdx.x - 128, t, false, red);
        return;
    }
    const int wv = t >> 6, lane = t & 63;
    const int pj = blockIdx.x * 16 + wv;               // 0..2047
    const int c = pj >> 4, blk = pj & 15;
    const int b = blk * 16 + (lane & 15);
    const int s0 = c * 32 + 8 * (lane >> 4);
    const float4 v0 = reinterpret_cast<const float4*>(&x[b * LENGTH + s0])[0];
    const float4 v1 = reinterpret_cast<const float4*>(&x[b * LENGTH + s0])[1];
    const float f[8] = {v0.x, v0.y, v0.z, v0.w, v1.x, v1.y, v1.z, v1.w};
    bf16x8 hv, lv;
#pragma unroll
    for (int e = 0; e < 8; ++e) {
        short h, l;
        split2(f[e], h, l);
        hv[e] = h; lv[e] = l;
    }
    const int off = (pj * 64 + lane) * 8;
    *reinterpret_cast<bf16x8*>(XH + off) = hv;
    *reinterpret_cast<bf16x8*>(XL + off) = lv;
}

// ---- generic squaring: D = S*S (plain / transposed store) ----
__global__ __launch_bounds__(1024) void mmsq(const float* __restrict__ S,
                                             float* __restrict__ D) {
    __shared__ float red[3 * 256];
    mm_body(S, S, D, blockIdx.x, threadIdx.x, false, red);
}
__global__ __launch_bounds__(1024) void mmsqT(const float* __restrict__ S,
                                              float* __restrict__ D) {
    __shared__ float red[3 * 256];
    mm_body(S, S, D, blockIdx.x, threadIdx.x, true, red);
}

// ---- L7: chains, SPILL-FREE. 6 blocks x 256 thr.
// blocks 0..3: W[16c+s] = (C A^{16c}) A^s, 16 steps stepping A.
// blocks 4..5: V[2s+c] = (A^128)^s (A^{64c} B), 32 steps stepping P128T.
// Step form (both): cur_new[j] = sum_i cur[i] * M[i*256+j], M column j held
// per-thread: i<176 in areg (VGPR), i>=176 in Alds rows (80 KB LDS).
__global__ __launch_bounds__(256) void chains(const float* __restrict__ A,
                                              const float* __restrict__ P16,
                                              const float* __restrict__ P32,
                                              const float* __restrict__ P64T,
                                              const float* __restrict__ P128T,
                                              const float* __restrict__ B,
                                              const float* __restrict__ C,
                                              float* __restrict__ Wm,
                                              float* __restrict__ Vm) {
    const int bidx = blockIdx.x;       // 0..5
    const int j = threadIdx.x;
    __shared__ float cur[256];
    __shared__ __align__(16) float Alds[80][256];   // rows 176..255 of M
    const float* M = (bidx < 4) ? A : P128T;

    float areg[176];
#pragma unroll 4
    for (int i = 0; i < 176; ++i) areg[i] = M[i * 256 + j];
    for (int r = 0; r < 80; ++r) Alds[r][j] = M[(176 + r) * 256 + j];

    // ---- start vector ----
    float sv;
    if (bidx == 0) {
        sv = C[j];
    } else if (bidx == 4) {
        sv = B[j];
    } else if (bidx == 5) {            // cur[i] = sum_k P64T[k*256+i] B[k]
        float a0 = 0.f, a1 = 0.f, a2 = 0.f, a3 = 0.f;
        for (int k = 0; k < 256; k += 4) {
            a0 = fmaf(B[k + 0], P64T[(k + 0) * 256 + j], a0);
            a1 = fmaf(B[k + 1], P64T[(k + 1) * 256 + j], a1);
            a2 = fmaf(B[k + 2], P64T[(k + 2) * 256 + j], a2);
            a3 = fmaf(B[k + 3], P64T[(k + 3) * 256 + j], a3);
        }
        sv = (a0 + a1) + (a2 + a3);
    } else {                           // 1,2,3: C * (P16|P32)
        const float* M1 = (bidx == 2) ? P32 : P16;
        float a0 = 0.f, a1 = 0.f, a2 = 0.f, a3 = 0.f;
        for (int i = 0; i < 256; i += 4) {
            a0 = fmaf(C[i + 0], M1[(i + 0) * 256 + j], a0);
            a1 = fmaf(C[i + 1], M1[(i + 1) * 256 + j], a1);
            a2 = fmaf(C[i + 2], M1[(i + 2) * 256 + j], a2);
            a3 = fmaf(C[i + 3], M1[(i + 3) * 256 + j], a3);
        }
        sv = (a0 + a1) + (a2 + a3);
    }
    if (bidx == 3) {                   // second factor: * P32
        cur[j] = sv;
        __syncthreads();
        float a0 = 0.f, a1 = 0.f, a2 = 0.f, a3 = 0.f;
        for (int i = 0; i < 256; i += 4) {
            a0 = fmaf(cur[i + 0], P32[(i + 0) * 256 + j], a0);
            a1 = fmaf(cur[i + 1], P32[(i + 1) * 256 + j], a1);
            a2 = fmaf(cur[i + 2], P32[(i + 2) * 256 + j], a2);
            a3 = fmaf(cur[i + 3], P32[(i + 3) * 256 + j], a3);
        }
        sv = (a0 + a1) + (a2 + a3);
        __syncthreads();
    }
    cur[j] = sv;
    __syncthreads();

    const int nst = (bidx < 4) ? 16 : 32;
    for (int s = 0; s < nst; ++s) {
        if (bidx < 4) Wm[(16 * bidx + s) * 256 + j] = cur[j];
        else          Vm[(2 * s + (bidx - 4)) * 256 + j] = cur[j];
        if (s == nst - 1) break;
        float a0 = 0.f, a1 = 0.f, a2 = 0.f, a3 = 0.f;
#pragma unroll
        for (int i = 0; i < 176; i += 4) {
            const float4 c4 = *reinterpret_cast<const float4*>(&cur[i]);
            a0 = fmaf(c4.x, areg[i + 0], a0);
            a1 = fmaf(c4.y, areg[i + 1], a1);
            a2 = fmaf(c4.z, areg[i + 2], a2);
            a3 = fmaf(c4.w, areg[i + 3], a3);
        }
#pragma unroll
        for (int r = 0; r < 80; r += 4) {
            const float4 c4 = *reinterpret_cast<const float4*>(&cur[176 + r]);
            a0 = fmaf(c4.x, Alds[r + 0][j], a0);
            a1 = fmaf(c4.y, Alds[r + 1][j], a1);
            a2 = fmaf(c4.z, Alds[r + 2][j], a2);
            a3 = fmaf(c4.w, Alds[r + 3][j], a3);
        }
        const float nv = (a0 + a1) + (a2 + a3);
        __syncthreads();
        cur[j] = nv;
        __syncthreads();
    }
}

// ---- L8: kfrag (32 blocks x 512 thr): K dots + Toeplitz A-fragments ----
// fragment m needs k[16m-31 .. 16m+127] -> kl window 159 wide (validated r8-r10)
__global__ __launch_bounds__(512) void kfrag(const float* __restrict__ Wm,
                                             const float* __restrict__ Vm,
                                             short* __restrict__ AH,
                                             short* __restrict__ AL) {
    const int bid = blockIdx.x, t = threadIdx.x;
    __shared__ float Wl[64 * 257];
    __shared__ float Vl[768];
    __shared__ float kl[160];
    for (int u = t; u < 16384; u += 512)
        Wl[(u >> 8) * 257 + (u & 255)] = Wm[u];
    for (int u = t; u < 768; u += 512) {
        const int q = 2 * bid - 1 + (u >> 8);
        Vl[u] = (q >= 0) ? Vm[q * 256 + (u & 255)] : 0.f;
    }
    __syncthreads();
    if (t < 159) {
        const int tau = 128 * bid - 31 + t;
        float s = 0.f;
        if (tau >= 0) {
            const int r = tau & 63;
            const int qq = (tau >> 6) - (2 * bid - 1);
            const float* wr = &Wl[r * 257];
            const float* vr = &Vl[qq * 256];
            float s0 = 0.f, s1 = 0.f, s2 = 0.f, s3 = 0.f;
#pragma unroll 8
            for (int i2 = 0; i2 < 256; i2 += 4) {
                s0 = fmaf(wr[i2 + 0], vr[i2 + 0], s0);
                s1 = fmaf(wr[i2 + 1], vr[i2 + 1], s1);
                s2 = fmaf(wr[i2 + 2], vr[i2 + 2], s2);
                s3 = fmaf(wr[i2 + 3], vr[i2 + 3], s3);
            }
            s = (s0 + s1) + (s2 + s3);
        }
        kl[t] = s;
    }
    __syncthreads();
    const int wv = t >> 6, lane = t & 63;
    const int m = 8 * bid + wv;
    bf16x8 hv, lv;
#pragma unroll
    for (int el = 0; el < 8; ++el) {
        const int rel = 16 * wv + (lane & 15) - 8 * (lane >> 4) - el + 31;
        short h_, l_;
        split2(kl[rel], h_, l_);          // rel always in [0,158]
        hv[el] = h_; lv[el] = l_;
    }
    const int off = (m * 64 + lane) * 8;
    *reinterpret_cast<bf16x8*>(AH + off) = hv;
    *reinterpret_cast<bf16x8*>(AL + off) = lv;
}

// ===========================================================================
// convm — validated (r4/r10): 256 blocks = 32 pairs x 8 btiles(32b); 8 waves
// k-split the pair's 130 chunks; double-buffered fragments; LDS reduce;
// coalesced exclusive float4 stores with D*x and t=0 fix folded in.
// ===========================================================================
struct Frag {
    bf16x8 bh0, bh1, bl0, bl1;
    bf16x8 ah0, ah1, ah2, ah3, al0, al1, al2, al3;
    int d0, tile;
};

#define LOADF(F, IDX_) do {                                                    \
        const int i_ = (IDX_);                                                 \
        const int tl_ = (i_ < nA) ? 0 : 1;                                     \
        const int cc_ = i_ - (tl_ ? nA : 0);                                   \
        const int xo_ = ((cc_ * 16 + bt2) * 64 + lane) * 8;                    \
        F.bh0 = *reinterpret_cast<const bf16x8*>(XH + xo_);                    \
        F.bh1 = *reinterpret_cast<const bf16x8*>(XH + xo_ + 512);              \
        F.bl0 = *reinterpret_cast<const bf16x8*>(XL + xo_);                    \
        F.bl1 = *reinterpret_cast<const bf16x8*>(XL + xo_ + 512);              \
        const int d_ = (tl_ ? tB64 : tA64) - cc_ * 32;                         \
        F.d0 = d_; F.tile = tl_;                                               \
        const int m0_ = (d_ > 0 ? d_ : 0) >> 4;                                \
        const int m1_ = (d_ + 16 > 0 ? d_ + 16 : 0) >> 4;                      \
        const int m2_ = (d_ + 32 > 0 ? d_ + 32 : 0) >> 4;                      \
        const int m3_ = (d_ + 48 > 0 ? d_ + 48 : 0) >> 4;                      \
        F.ah0 = *reinterpret_cast<const bf16x8*>(AH + (m0_ * 64 + lane) * 8);  \
        F.al0 = *reinterpret_cast<const bf16x8*>(AL + (m0_ * 64 + lane) * 8);  \
        F.ah1 = *reinterpret_cast<const bf16x8*>(AH + (m1_ * 64 + lane) * 8);  \
        F.al1 = *reinterpret_cast<const bf16x8*>(AL + (m1_ * 64 + lane) * 8);  \
        F.ah2 = *reinterpret_cast<const bf16x8*>(AH + (m2_ * 64 + lane) * 8);  \
        F.al2 = *reinterpret_cast<const bf16x8*>(AL + (m2_ * 64 + lane) * 8);  \
        F.ah3 = *reinterpret_cast<const bf16x8*>(AH + (m3_ * 64 + lane) * 8);  \
        F.al3 = *reinterpret_cast<const bf16x8*>(AL + (m3_ * 64 + lane) * 8);  \
    } while (0)

#define ONER(F, T, R, AHF, ALF)                                                \
        if (F.d0 + 16 * R >= 0) {                                              \
            acc[T][R][0] = MFMA(F.AHF, F.bh0, acc[T][R][0]);                   \
            acc[T][R][1] = MFMA(F.AHF, F.bh1, acc[T][R][1]);                   \
            acc[T][R][0] = MFMA(F.AHF, F.bl0, acc[T][R][0]);                   \
            acc[T][R][1] = MFMA(F.AHF, F.bl1, acc[T][R][1]);                   \
            acc[T][R][0] = MFMA(F.ALF, F.bh0, acc[T][R][0]);                   \
            acc[T][R][1] = MFMA(F.ALF, F.bh1, acc[T][R][1]);                   \
        }

#define APPLY(F) do {                                                          \
        if (F.tile == 0) {                                                     \
            ONER(F, 0, 0, ah0, al0) ONER(F, 0, 1, ah1, al1)                    \
            ONER(F, 0, 2, ah2, al2) ONER(F, 0, 3, ah3, al3)                    \
        } else {                                                               \
            ONER(F, 1, 0, ah0, al0) ONER(F, 1, 1, ah1, al1)                    \
            ONER(F, 1, 2, ah2, al2) ONER(F, 1, 3, ah3, al3)                    \
        }                                                                      \
    } while (0)

__global__ __launch_bounds__(512) void convm(const short* __restrict__ XH,
                                             const short* __restrict__ XL,
                                             const short* __restrict__ AH,
                                             const short* __restrict__ AL,
                                             const float* __restrict__ x,
                                             const float* __restrict__ Dp,
                                             float* __restrict__ out) {
    const int pr = blockIdx.x & 31;
    const int bt = blockIdx.x >> 5;
    const int tid = threadIdx.x;
    const int w = tid >> 6, lane = tid & 63;
    const int tA64 = pr * 64, tB64 = (63 - pr) * 64;
    const int nA = 2 * pr + 2;
    const int bt2 = bt * 2;

    __shared__ float lds[16 * 64 * 34];

    f32x4 acc[2][4][2];
#pragma unroll
    for (int t_ = 0; t_ < 2; ++t_)
#pragma unroll
        for (int r_ = 0; r_ < 4; ++r_)
#pragma unroll
            for (int c_ = 0; c_ < 2; ++c_) acc[t_][r_][c_] = f32x4{0.f, 0.f, 0.f, 0.f};

    Frag f0, f1;
    LOADF(f0, w);
    int idx = w;
    while (true) {
        const int n1 = idx + 8;
        const bool h1 = n1 < 130;
        if (h1) LOADF(f1, n1);
        APPLY(f0);
        if (!h1) break;
        const int n2 = n1 + 8;
        const bool h2 = n2 < 130;
        if (h2) LOADF(f0, n2);
        APPLY(f1);
        if (!h2) break;
        idx = n2;
    }

    const int lq = lane >> 4, lr = lane & 15;
#pragma unroll
    for (int t_ = 0; t_ < 2; ++t_)
#pragma unroll
        for (int r_ = 0; r_ < 4; ++r_)
#pragma unroll
            for (int c_ = 0; c_ < 2; ++c_)
#pragma unroll
                for (int e_ = 0; e_ < 4; ++e_)
                    lds[((w * 2 + t_) * 64 + (r_ * 16 + lq * 4 + e_)) * 34 +
                        (c_ * 16 + lr)] = acc[t_][r_][c_][e_];
    __syncthreads();

    const float D = Dp[0];
    const int b = tid >> 4;
    const int t4 = (tid & 15) * 4;
#pragma unroll
    for (int t_ = 0; t_ < 2; ++t_) {
        const int tbase = t_ ? tB64 : tA64;
        float s0 = 0.f, s1 = 0.f, s2 = 0.f, s3 = 0.f;
#pragma unroll
        for (int w_ = 0; w_ < 8; ++w_) {
            const float* lp = &lds[((w_ * 2 + t_) * 64 + t4) * 34 + b];
            s0 += lp[0]; s1 += lp[34]; s2 += lp[68]; s3 += lp[102];
        }
        const int g = (bt * 32 + b) * LENGTH + tbase + t4;
        const float4 xv = *reinterpret_cast<const float4*>(x + g);
        float4 o;
        o.x = 2.f * s0 + D * xv.x;
        o.y = 2.f * s1 + D * xv.y;
        o.z = 2.f * s2 + D * xv.z;
        o.w = 2.f * s3 + D * xv.w;
        if (tbase == 0 && t4 == 0) o.x -= s0;     // t==0: fac is 1, not 2
        *reinterpret_cast<float4*>(out + g) = o;
    }
}

extern "C" void kernel_launch(void* const* d_in, const int* in_sizes, int n_in,
                              void* d_out, int out_size, void* d_ws, size_t ws_size,
                              hipStream_t stream) {
    const float* x  = (const float*)d_in[0];
    const float* A  = (const float*)d_in[1];
    const float* B  = (const float*)d_in[2];
    const float* C  = (const float*)d_in[3];
    const float* Dp = (const float*)d_in[4];
    float* out = (float*)d_out;
    float* ws  = (float*)d_ws;

    float* P2    = ws + WS_P2;
    float* P4    = ws + WS_P4;
    float* P8    = ws + WS_P8;
    float* P16   = ws + WS_P16;
    float* P32   = ws + WS_P32;
    float* P64T  = ws + WS_P64T;
    float* P128T = ws + WS_P128T;
    float* Wm    = ws + WS_W;
    float* Vm    = ws + WS_V;
    short* XHs   = (short*)(ws + WS_XH);
    short* XLs   = (short*)(ws + WS_XL);
    short* AHs   = (short*)(ws + WS_AH);
    short* ALs   = (short*)(ws + WS_AL);

    fused0<<<384, 1024, 0, stream>>>(A, x, P2, XHs, XLs);
    mmsq<<<256, 1024, 0, stream>>>(P2, P4);
    mmsq<<<256, 1024, 0, stream>>>(P4, P8);
    mmsq<<<256, 1024, 0, stream>>>(P8, P16);
    mmsq<<<256, 1024, 0, stream>>>(P16, P32);
    mmsqT<<<256, 1024, 0, stream>>>(P32, P64T);
    mmsq<<<256, 1024, 0, stream>>>(P64T, P128T);
    chains<<<6, 256, 0, stream>>>(A, P16, P32, P64T, P128T, B, C, Wm, Vm);
    kfrag<<<32, 512, 0, stream>>>(Wm, Vm, AHs, ALs);
    convm<<<256, 512, 0, stream>>>(XHs, XLs, AHs, ALs, x, Dp, out);
}